// Round 16
// baseline (240.125 us; speedup 1.0000x reference)
//
#include <hip/hip_runtime.h>

typedef __attribute__((ext_vector_type(4))) float f32x4;
typedef __attribute__((ext_vector_type(8))) short bf16x8;
typedef __attribute__((ext_vector_type(4))) short bf16x4;

#define MFMA16(a, b, c) __builtin_amdgcn_mfma_f32_16x16x32_bf16((a), (b), (c), 0, 0, 0)
#define LOG2E 1.44269504088896340736f

static __device__ __forceinline__ float bf2f(short u) {
  unsigned x = ((unsigned)(unsigned short)u) << 16;
  return __builtin_bit_cast(float, x);
}
static __device__ __forceinline__ short f2bf(float f) {
  unsigned u = __builtin_bit_cast(unsigned, f);
  u += 0x7fffu + ((u >> 16) & 1u);
  return (short)(u >> 16);
}
// global -> LDS direct DMA, 16B per lane (guide §5); source pre-swizzled.
static __device__ __forceinline__ void gll16(const void* g, void* l) {
  __builtin_amdgcn_global_load_lds(
      (const __attribute__((address_space(1))) unsigned*)(unsigned long long)g,
      (__attribute__((address_space(3))) unsigned*)(unsigned)(unsigned long long)l,
      16, 0, 0);
}

// --- merged setup: f32->bf16 cvt (h,Wq,Wk,Wv) + rope table + bias concat ---
__global__ void __launch_bounds__(256) setup_all(const float* __restrict__ h,
                                                 const float* __restrict__ wq,
                                                 const float* __restrict__ wk,
                                                 const float* __restrict__ wv,
                                                 short* __restrict__ hbf,
                                                 short* __restrict__ wall,
                                                 const int* __restrict__ pos,
                                                 float* __restrict__ ctab,
                                                 float* __restrict__ stab,
                                                 const float* __restrict__ bq,
                                                 const float* __restrict__ bk,
                                                 const float* __restrict__ bv,
                                                 float* __restrict__ ball) {
  const int bid = (int)blockIdx.x;
  const int tid = (int)threadIdx.x;
  if (bid >= 2048) {
    const int rb = bid - 2048;  // 0..255
    if (rb < 18) {
      const int i = rb * 256 + tid;
      if (i < 3584) ball[i] = bq[i];
      else if (i < 4096) ball[i] = bk[i - 3584];
      else if (i < 4608) ball[i] = bv[i - 4096];
    }
#pragma unroll
    for (int e = 0; e < 2; ++e) {
      const int ii = (rb * 256 + tid) * 2 + e;  // 0..131071
      const int s = ii >> 6, i = ii & 63;
      const float p = (float)pos[s];
      const float ang = p * exp2f(-(float)i * 0.3114307588956902f);
      ctab[s * 64 + i] = cosf(ang);
      stab[s * 64 + i] = sinf(ang);
    }
    return;
  }
  const long long C0 = 917504, C1 = 1605632, C2 = 229376;  // 8-elem chunks
  long long ch = (long long)bid * 256 + tid;
  const long long stride = (long long)2048 * 256;
  const long long total = C0 + C1 + 2 * C2;
  for (; ch < total; ch += stride) {
    const float* s;
    short* d;
    long long off;
    if (ch < C0) { s = h; d = hbf; off = ch; }
    else if (ch < C0 + C1) { s = wq; d = wall; off = ch - C0; }
    else if (ch < C0 + C1 + C2) { s = wk; d = wall + (size_t)3584 * 3584; off = ch - C0 - C1; }
    else { s = wv; d = wall + (size_t)4096 * 3584; off = ch - C0 - C1 - C2; }
    const long long i = off * 8;
    f32x4 a = *(const f32x4*)(s + i);
    f32x4 b = *(const f32x4*)(s + i + 4);
    bf16x8 o;
    o[0] = f2bf(a[0]); o[1] = f2bf(a[1]); o[2] = f2bf(a[2]); o[3] = f2bf(a[3]);
    o[4] = f2bf(b[0]); o[5] = f2bf(b[1]); o[6] = f2bf(b[2]); o[7] = f2bf(b[3]);
    *(bf16x8*)(d + i) = o;
  }
}

// --- fused RoPE (in-place on qkv q/k regions) + V transpose -> vtb ---------
__global__ void __launch_bounds__(256) rope_vt(short* __restrict__ qkv,
                                               const float* __restrict__ ctab,
                                               const float* __restrict__ stab,
                                               short* __restrict__ vtb) {
  const int bid = (int)blockIdx.x;
  const int tid = (int)threadIdx.x;
  if (bid >= 2048) {
    __shared__ short t[64 * 48];
    const int vb = bid - 2048;  // 0..511
    const int dt = vb & 3, st = (vb >> 2) & 31, kv = vb >> 7;
    {
      const int r = tid >> 2, c8 = tid & 3;
      const bf16x8 v = *(const bf16x8*)(qkv + (size_t)(st * 64 + r) * 4608 + 4096 +
                                        kv * 128 + dt * 32 + c8 * 8);
      *(bf16x8*)(t + r * 48 + c8 * 8) = v;
    }
    __syncthreads();
    {
      const int d = tid >> 3, c = tid & 7;
      bf16x8 v;
#pragma unroll
      for (int i = 0; i < 8; ++i) v[i] = t[(c * 8 + i) * 48 + d];
      *(bf16x8*)(vtb + ((size_t)kv * 128 + dt * 32 + d) * 2048 + st * 64 + c * 8) = v;
    }
    return;
  }
  const int idx = bid * 256 + tid;  // 2048*32*8
  const int c = idx & 7;
  const int h = (idx >> 3) & 31;
  const int s = idx >> 8;
  const float qs = (h < 28) ? (0.08838834764831845f * LOG2E) : 1.0f;
  short* base = qkv + (size_t)s * 4608 + h * 128 + c * 8;
  bf16x8 lo = *(bf16x8*)base;
  bf16x8 hi = *(bf16x8*)(base + 64);
  const float* cp = ctab + s * 64 + c * 8;
  const float* sp = stab + s * 64 + c * 8;
  bf16x8 lo2, hi2;
#pragma unroll
  for (int j = 0; j < 8; ++j) {
    const float x = bf2f(lo[j]), y = bf2f(hi[j]);
    const float cv = cp[j], sv = sp[j];
    lo2[j] = f2bf((x * cv - y * sv) * qs);
    hi2[j] = f2bf((y * cv + x * sv) * qs);
  }
  *(bf16x8*)base = lo2;
  *(bf16x8*)(base + 64) = hi2;
}

// --- 4-phase bf16 GEMM (r15-proven engine): QKV full-K + hetero Wo cvt ------
template <int BM, int NT, int MCH, int NCH, bool BIAS, bool OUTBF, bool HETERO>
__global__ void __launch_bounds__(512, 2)
gemm11(const short* __restrict__ A, const short* __restrict__ B,
       const float* __restrict__ bias, void* __restrict__ outp, int N, int K,
       const float* __restrict__ xsrc, short* __restrict__ xdst) {
  constexpr int MQ2 = BM / 64;
  constexpr int ACH = BM / 128;
  __shared__ short As[2][BM * 64];
  __shared__ short Bs[2][256 * 64];
  const int bid = (int)blockIdx.x;
  const int tid = (int)threadIdx.x;
  if (HETERO && (bid >> 3) >= MCH * NCH) {
    const int cb = bid - 8 * MCH * NCH;  // 0..111
    long long i = ((long long)cb * 512 + tid) * 8;
    const long long stride = (long long)112 * 512 * 8;
    const long long n = (long long)3584 * 3584;
    for (; i < n; i += stride) {
      f32x4 a = *(const f32x4*)(xsrc + i);
      f32x4 b = *(const f32x4*)(xsrc + i + 4);
      bf16x8 o;
      o[0] = f2bf(a[0]); o[1] = f2bf(a[1]); o[2] = f2bf(a[2]); o[3] = f2bf(a[3]);
      o[4] = f2bf(b[0]); o[5] = f2bf(b[1]); o[6] = f2bf(b[2]); o[7] = f2bf(b[3]);
      *(bf16x8*)(xdst + i) = o;
    }
    return;
  }
  const int xcd = bid & 7, idx = bid >> 3;
  const int rowg = xcd / (NT / NCH), colg = xcd % (NT / NCH);
  const int tm = (rowg * MCH + idx % MCH) * BM;
  const int tn = (colg * NCH + idx / MCH) * 256;
  const int wave = tid >> 6, lane = tid & 63;
  const int l15 = lane & 15, g = lane >> 4;
  const int wm = wave >> 2, wn = wave & 3;

  f32x4 acc[2][MQ2][2][2] = {};
  bf16x8 af[MQ2][2], b0[2][2], b1[2][2];

#define STG_A(b, kt, h)                                                         \
  { _Pragma("unroll") for (int j = 0; j < ACH; ++j) {                           \
      const int lr = (h) * (BM / 2) + j * 64 + (tid >> 3);                      \
      const int wmm = (lr / (BM / 4)) & 1;                                      \
      const int rr = lr & (BM / 4 - 1);                                         \
      const int grow = wmm * (BM / 2) + (h) * (BM / 4) + rr;                    \
      const int sc = (tid & 7) ^ (rr & 7);                                      \
      gll16(A + (size_t)(tm + grow) * K + (size_t)(kt) * 64 + sc * 8,           \
            &As[b][((h) * (BM / 2) + j * 64 + wave * 8) * 64]);                 \
    } }
#define STG_B(b, kt, h)                                                         \
  { _Pragma("unroll") for (int j = 0; j < 2; ++j) {                             \
      const int lr = (h) * 128 + j * 64 + (tid >> 3);                           \
      const int wnn = (lr >> 5) & 3;                                            \
      const int rr = lr & 31;                                                   \
      const int gcol = wnn * 64 + (h) * 32 + rr;                                \
      const int sc = (tid & 7) ^ (rr & 7);                                      \
      gll16(B + (size_t)(tn + gcol) * K + (size_t)(kt) * 64 + sc * 8,           \
            &Bs[b][((h) * 128 + j * 64 + wave * 8) * 64]);                      \
    } }
#define LDA(buf, rh)                                                            \
  { _Pragma("unroll") for (int mq = 0; mq < MQ2; ++mq)                          \
      _Pragma("unroll") for (int ks = 0; ks < 2; ++ks) {                        \
        const int lr = (rh) * (BM / 2) + wm * (BM / 4) + mq * 16 + l15;         \
        af[mq][ks] =                                                            \
            *(const bf16x8*)(&As[buf][lr * 64 + (((ks * 4 + g) ^ (lr & 7)) * 8)]); \
      } }
#define LDB(buf, ch, ARR)                                                       \
  { _Pragma("unroll") for (int nq = 0; nq < 2; ++nq)                            \
      _Pragma("unroll") for (int ks = 0; ks < 2; ++ks) {                        \
        const int lr = (ch) * 128 + wn * 32 + nq * 16 + l15;                    \
        ARR[nq][ks] =                                                           \
            *(const bf16x8*)(&Bs[buf][lr * 64 + (((ks * 4 + g) ^ (lr & 7)) * 8)]); \
      } }
#define VMW()                                                                   \
  { if constexpr (ACH == 2) { asm volatile("s_waitcnt vmcnt(6)" ::: "memory"); }\
    else { asm volatile("s_waitcnt vmcnt(5)" ::: "memory"); } }
#define PHM(RH, TAILBLK)                                                        \
  {                                                                             \
    __builtin_amdgcn_s_barrier();                                               \
    asm volatile("s_waitcnt lgkmcnt(0)" ::: "memory");                          \
    __builtin_amdgcn_sched_barrier(0);                                          \
    __builtin_amdgcn_s_setprio(1);                                              \
    _Pragma("unroll") for (int mq = 0; mq < MQ2; ++mq)                          \
      _Pragma("unroll") for (int nq = 0; nq < 2; ++nq) {                        \
        acc[RH][mq][0][nq] = MFMA16(af[mq][0], b0[nq][0], acc[RH][mq][0][nq]);  \
        acc[RH][mq][0][nq] = MFMA16(af[mq][1], b0[nq][1], acc[RH][mq][0][nq]);  \
        acc[RH][mq][1][nq] = MFMA16(af[mq][0], b1[nq][0], acc[RH][mq][1][nq]);  \
        acc[RH][mq][1][nq] = MFMA16(af[mq][1], b1[nq][1], acc[RH][mq][1][nq]);  \
      }                                                                         \
    __builtin_amdgcn_s_setprio(0);                                              \
    TAILBLK;                                                                    \
    __builtin_amdgcn_sched_barrier(0);                                          \
  }

  STG_A(0, 0, 0); STG_A(0, 0, 1); STG_B(0, 0, 0); STG_B(0, 0, 1);
  STG_A(1, 1, 0); STG_A(1, 1, 1); STG_B(1, 1, 0); STG_B(1, 1, 1);
  if constexpr (ACH == 2) { asm volatile("s_waitcnt vmcnt(8)" ::: "memory"); }
  else                    { asm volatile("s_waitcnt vmcnt(6)" ::: "memory"); }
  __builtin_amdgcn_s_barrier();
  LDA(0, 0); LDB(0, 0, b0); LDB(0, 1, b1);

  const int L = K >> 7;
  for (int i = 0; i < L; ++i) {
    const int t2 = 2 * i + 2, t3 = 2 * i + 3;
    const bool more = (i < L - 1);
    PHM(0, {
      if (more) { STG_A(0, t2, 0); STG_B(0, t2, 0); STG_B(0, t2, 1); VMW(); }
      else { asm volatile("s_waitcnt vmcnt(0)" ::: "memory"); }
      LDA(0, 1);
    });
    PHM(1, {
      if (more) STG_A(0, t2, 1);
      LDA(1, 0); LDB(1, 0, b0); LDB(1, 1, b1);
    });
    PHM(0, {
      if (more) { STG_A(1, t3, 0); STG_B(1, t3, 0); STG_B(1, t3, 1); VMW(); }
      LDA(1, 1);
    });
    PHM(1, {
      if (more) { STG_A(1, t3, 1); LDA(0, 0); LDB(0, 0, b0); LDB(0, 1, b1); }
    });
  }

#pragma unroll
  for (int rh = 0; rh < 2; ++rh)
#pragma unroll
    for (int mq = 0; mq < MQ2; ++mq)
#pragma unroll
      for (int ch = 0; ch < 2; ++ch)
#pragma unroll
        for (int nq = 0; nq < 2; ++nq) {
          const int col = tn + wn * 64 + ch * 32 + nq * 16 + l15;
          const float bv = BIAS ? bias[col] : 0.0f;
          const int row0 = tm + wm * (BM / 2) + rh * (BM / 4) + mq * 16 + g * 4;
#pragma unroll
          for (int r = 0; r < 4; ++r) {
            const float v = acc[rh][mq][ch][nq][r] + bv;
            if (OUTBF) ((short*)outp)[(size_t)(row0 + r) * N + col] = f2bf(v);
            else       ((float*)outp)[(size_t)(row0 + r) * N + col] = v;
          }
        }
#undef STG_A
#undef STG_B
#undef LDA
#undef LDB
#undef VMW
#undef PHM
}

// --- O-proj split-K-2: same engine, 28 K-tiles/block, LDS-repack epilogue ---
// 224 blocks: xcd=bid&7 owns a 2Mx7N rect; idx=bid>>3 (0..27): t=idx>>1 picks
// the tile (tmi=rowg*2+(t&1), tni=colg*7+(t>>1)), half=idx&1 -> koff=28*half.
// Both halves of a tile in the same XCD (lockstep L2 sharing preserved).
// Epilogue: acc -> Es (32KB; LDS total 160KB) -> FULL-512B-row stores to
// row-major bf16 partial slot (r12-proven, no partial cache lines).
__global__ void __launch_bounds__(512, 2)
gemm_osp(const short* __restrict__ A, const short* __restrict__ B,
         short* __restrict__ Pp, int K) {
  __shared__ short As[2][256 * 64];
  __shared__ short Bs[2][256 * 64];
  __shared__ short Es[64 * 256];
  const int bid = (int)blockIdx.x;
  const int tid = (int)threadIdx.x;
  const int xcd = bid & 7, idx = bid >> 3;
  const int rowg = xcd >> 1, colg = xcd & 1;
  const int t = idx >> 1, half = idx & 1;
  const int tmi = rowg * 2 + (t & 1);
  const int tni = colg * 7 + (t >> 1);
  const int tm = tmi << 8, tn = tni << 8;
  const int koff = half * 28;
  const int slot = (tmi * 14 + tni) * 2 + half;
  const int wave = tid >> 6, lane = tid & 63;
  const int l15 = lane & 15, g = lane >> 4;
  const int wm = wave >> 2, wn = wave & 3;

  f32x4 acc[2][4][2][2] = {};
  bf16x8 af[4][2], b0[2][2], b1[2][2];

#define STG_A(b, kt, h)                                                         \
  { _Pragma("unroll") for (int j = 0; j < 2; ++j) {                             \
      const int lr = (h) * 128 + j * 64 + (tid >> 3);                           \
      const int wmm = (lr >> 6) & 1;                                            \
      const int rr = lr & 63;                                                   \
      const int grow = wmm * 128 + (h) * 64 + rr;                               \
      const int sc = (tid & 7) ^ (rr & 7);                                      \
      gll16(A + (size_t)(tm + grow) * K + (size_t)(kt) * 64 + sc * 8,           \
            &As[b][((h) * 128 + j * 64 + wave * 8) * 64]);                      \
    } }
#define STG_B(b, kt, h)                                                         \
  { _Pragma("unroll") for (int j = 0; j < 2; ++j) {                             \
      const int lr = (h) * 128 + j * 64 + (tid >> 3);                           \
      const int wnn = (lr >> 5) & 3;                                            \
      const int rr = lr & 31;                                                   \
      const int gcol = wnn * 64 + (h) * 32 + rr;                                \
      const int sc = (tid & 7) ^ (rr & 7);                                      \
      gll16(B + (size_t)(tn + gcol) * K + (size_t)(kt) * 64 + sc * 8,           \
            &Bs[b][((h) * 128 + j * 64 + wave * 8) * 64]);                      \
    } }
#define LDA(buf, rh)                                                            \
  { _Pragma("unroll") for (int mq = 0; mq < 4; ++mq)                            \
      _Pragma("unroll") for (int ks = 0; ks < 2; ++ks) {                        \
        const int lr = (rh) * 128 + wm * 64 + mq * 16 + l15;                    \
        af[mq][ks] =                                                            \
            *(const bf16x8*)(&As[buf][lr * 64 + (((ks * 4 + g) ^ (lr & 7)) * 8)]); \
      } }
#define LDB(buf, ch, ARR)                                                       \
  { _Pragma("unroll") for (int nq = 0; nq < 2; ++nq)                            \
      _Pragma("unroll") for (int ks = 0; ks < 2; ++ks) {                        \
        const int lr = (ch) * 128 + wn * 32 + nq * 16 + l15;                    \
        ARR[nq][ks] =                                                           \
            *(const bf16x8*)(&Bs[buf][lr * 64 + (((ks * 4 + g) ^ (lr & 7)) * 8)]); \
      } }
#define VMW() { asm volatile("s_waitcnt vmcnt(6)" ::: "memory"); }
#define PHM(RH, TAILBLK)                                                        \
  {                                                                             \
    __builtin_amdgcn_s_barrier();                                               \
    asm volatile("s_waitcnt lgkmcnt(0)" ::: "memory");                          \
    __builtin_amdgcn_sched_barrier(0);                                          \
    __builtin_amdgcn_s_setprio(1);                                              \
    _Pragma("unroll") for (int mq = 0; mq < 4; ++mq)                            \
      _Pragma("unroll") for (int nq = 0; nq < 2; ++nq) {                        \
        acc[RH][mq][0][nq] = MFMA16(af[mq][0], b0[nq][0], acc[RH][mq][0][nq]);  \
        acc[RH][mq][0][nq] = MFMA16(af[mq][1], b0[nq][1], acc[RH][mq][0][nq]);  \
        acc[RH][mq][1][nq] = MFMA16(af[mq][0], b1[nq][0], acc[RH][mq][1][nq]);  \
        acc[RH][mq][1][nq] = MFMA16(af[mq][1], b1[nq][1], acc[RH][mq][1][nq]);  \
      }                                                                         \
    __builtin_amdgcn_s_setprio(0);                                              \
    TAILBLK;                                                                    \
    __builtin_amdgcn_sched_barrier(0);                                          \
  }

  STG_A(0, koff + 0, 0); STG_A(0, koff + 0, 1);
  STG_B(0, koff + 0, 0); STG_B(0, koff + 0, 1);
  STG_A(1, koff + 1, 0); STG_A(1, koff + 1, 1);
  STG_B(1, koff + 1, 0); STG_B(1, koff + 1, 1);
  asm volatile("s_waitcnt vmcnt(8)" ::: "memory");
  __builtin_amdgcn_s_barrier();
  LDA(0, 0); LDB(0, 0, b0); LDB(0, 1, b1);

  for (int i = 0; i < 14; ++i) {
    const int t2 = koff + 2 * i + 2, t3 = koff + 2 * i + 3;
    const bool more = (i < 13);
    PHM(0, {
      if (more) { STG_A(0, t2, 0); STG_B(0, t2, 0); STG_B(0, t2, 1); VMW(); }
      else { asm volatile("s_waitcnt vmcnt(0)" ::: "memory"); }
      LDA(0, 1);
    });
    PHM(1, {
      if (more) STG_A(0, t2, 1);
      LDA(1, 0); LDB(1, 0, b0); LDB(1, 1, b1);
    });
    PHM(0, {
      if (more) { STG_A(1, t3, 0); STG_B(1, t3, 0); STG_B(1, t3, 1); VMW(); }
      LDA(1, 1);
    });
    PHM(1, {
      if (more) { STG_A(1, t3, 1); LDA(0, 0); LDB(0, 0, b0); LDB(0, 1, b1); }
    });
  }
#undef STG_A
#undef STG_B
#undef LDA
#undef LDB
#undef VMW
#undef PHM

  // LDS-repack epilogue (r12-proven): 4 row-groups of 64; scatter -> barrier
  // -> full-row coalesced stores (wave w rows w*8..+7, lane L cols 4L..4L+3).
  short* pb = Pp + (size_t)slot * 65536;
#pragma unroll
  for (int rg = 0; rg < 4; ++rg) {
    if (wm == (rg >> 1)) {
#pragma unroll
      for (int mq = 0; mq < 4; ++mq)
#pragma unroll
        for (int ch = 0; ch < 2; ++ch)
#pragma unroll
          for (int nq = 0; nq < 2; ++nq)
#pragma unroll
            for (int r = 0; r < 4; ++r)
              Es[(mq * 16 + g * 4 + r) * 256 + wn * 64 + ch * 32 + nq * 16 + l15] =
                  f2bf(acc[rg & 1][mq][ch][nq][r]);
    }
    asm volatile("s_waitcnt lgkmcnt(0)" ::: "memory");
    __builtin_amdgcn_s_barrier();
#pragma unroll
    for (int rr = 0; rr < 8; ++rr) {
      const int rl = wave * 8 + rr;
      *(bf16x4*)(pb + (size_t)(rg * 64 + rl) * 256 + lane * 4) =
          *(const bf16x4*)(&Es[rl * 256 + lane * 4]);
    }
    asm volatile("s_waitcnt lgkmcnt(0)" ::: "memory");
    __builtin_amdgcn_s_barrier();
  }
}

// O-proj reduce: out = partial(half0) + partial(half1), f32 (coalesced).
__global__ void __launch_bounds__(256) o_reduce(const short* __restrict__ Pp,
                                                float* __restrict__ out) {
  const int idx = blockIdx.x * 256 + threadIdx.x;  // 2048*448
  const int s = idx / 448;
  const int col0 = (idx % 448) * 8;
  const int tmi = s >> 8, tni = col0 >> 8;
  const size_t base = (size_t)((tmi * 14 + tni) * 2) * 65536;
  const size_t off = (size_t)(s & 255) * 256 + (col0 & 255);
  const bf16x8 a = *(const bf16x8*)(Pp + base + off);
  const bf16x8 b = *(const bf16x8*)(Pp + base + 65536 + off);
  f32x4 o1, o2;
#pragma unroll
  for (int q = 0; q < 4; ++q) {
    o1[q] = bf2f(a[q]) + bf2f(b[q]);
    o2[q] = bf2f(a[q + 4]) + bf2f(b[q + 4]);
  }
  float* dst = out + (size_t)s * 3584 + col0;
  *(f32x4*)dst = o1;
  *(f32x4*)(dst + 4) = o2;
}

// ------- flash attention, 2-phase pipelined, 896 blocks (longest-first) -----
__global__ void __launch_bounds__(256) attn_kernel(const short* __restrict__ qkv,
                                                   const short* __restrict__ vtb,
                                                   short* __restrict__ outb) {
  const int lid = (int)blockIdx.x;   // 0..895, dispatched in order
  const int head = lid % 28;
  const int qt = 31 - lid / 28;      // longest q-tiles first
  const int kvh = head / 7;

  const int tid = threadIdx.x;
  const int lane = tid & 63, wave = tid >> 6;
  const int l15 = lane & 15, g = lane >> 4;

  __shared__ short Ks[2][64 * 128];
  __shared__ short Vs[2][128 * 64];
  __shared__ short Ps[4][16 * 64];

  const short* kbase = qkv + 3584 + kvh * 128;
  const short* vbase = vtb + (size_t)kvh * 128 * 2048;
  const float NINF = -__builtin_inff();

  bf16x8 qf[4];
  {
    const short* qptr = qkv + (size_t)(qt * 64 + wave * 16 + l15) * 4608 + head * 128 + g * 8;
#pragma unroll
    for (int ds = 0; ds < 4; ++ds) qf[ds] = *(const bf16x8*)(qptr + ds * 32);
  }
  f32x4 o[8] = {};
  float mrun[4] = {NINF, NINF, NINF, NINF};
  float lrun[4] = {0.f, 0.f, 0.f, 0.f};

#define STAGE(kv, b)                                                               \
  {                                                                                \
    _Pragma("unroll") for (int it = 0; it < 4; ++it) {                             \
      const int chunk = it * 256 + tid;                                            \
      const int row = chunk >> 4, sc = (chunk & 15) ^ (row & 7);                   \
      gll16(kbase + (size_t)((kv)*64 + row) * 4608 + sc * 8,                       \
            &Ks[b][(it * 256 + wave * 64) * 8]);                                   \
    }                                                                              \
    _Pragma("unroll") for (int it = 0; it < 4; ++it) {                             \
      const int chunk = it * 256 + tid;                                            \
      const int row = chunk >> 3, sc = (chunk & 7) ^ (row & 7);                    \
      gll16(vbase + (size_t)row * 2048 + (kv)*64 + sc * 8,                         \
            &Vs[b][(it * 256 + wave * 64) * 8]);                                   \
    }                                                                              \
  }

  STAGE(0, 0);
  __syncthreads();
  int cur = 0;

#pragma unroll 1
  for (int t = 0; t <= qt; ++t) {
    if (t < qt) STAGE(t + 1, cur ^ 1);
    const bool diag = (t == qt);

    f32x4 sf[4] = {};
    __builtin_amdgcn_s_setprio(1);
#pragma unroll
    for (int n = 0; n < 4; ++n) {
      const int krow = n * 16 + l15;
#pragma unroll
      for (int ds = 0; ds < 4; ++ds) {
        const int c = (ds * 4 + g) ^ (krow & 7);
        const bf16x8 kf = *(const bf16x8*)(&Ks[cur][krow * 128 + c * 8]);
        sf[n] = MFMA16(qf[ds], kf, sf[n]);
      }
    }
    __builtin_amdgcn_s_setprio(0);

    if (diag) {
#pragma unroll
      for (int r = 0; r < 4; ++r) {
        const int qr = qt * 64 + wave * 16 + g * 4 + r;
#pragma unroll
        for (int n = 0; n < 4; ++n)
          if (t * 64 + n * 16 + l15 > qr) sf[n][r] = NINF;
      }
    }
    float pmax[4];
#pragma unroll
    for (int r = 0; r < 4; ++r)
      pmax[r] = fmaxf(fmaxf(sf[0][r], sf[1][r]), fmaxf(sf[2][r], sf[3][r]));
    const bool need = (pmax[0] > mrun[0] + 8.f) || (pmax[1] > mrun[1] + 8.f) ||
                      (pmax[2] > mrun[2] + 8.f) || (pmax[3] > mrun[3] + 8.f);
    if (__any(need)) {
#pragma unroll
      for (int r = 0; r < 4; ++r) {
        float mx = pmax[r];
        mx = fmaxf(mx, __shfl_xor(mx, 1));
        mx = fmaxf(mx, __shfl_xor(mx, 2));
        mx = fmaxf(mx, __shfl_xor(mx, 4));
        mx = fmaxf(mx, __shfl_xor(mx, 8));
        const float mnew = fmaxf(mrun[r], mx);
        const float alpha = exp2f(mrun[r] - mnew);
        mrun[r] = mnew;
        lrun[r] *= alpha;
#pragma unroll
        for (int nd = 0; nd < 8; ++nd) o[nd][r] *= alpha;
      }
    }
#pragma unroll
    for (int n = 0; n < 4; ++n) {
#pragma unroll
      for (int r = 0; r < 4; ++r) {
        const float p = exp2f(sf[n][r] - mrun[r]);
        lrun[r] += p;
        const int prow = g * 4 + r, key = n * 16 + l15;
        const int cp = (key >> 3) ^ (prow & 7);
        Ps[wave][prow * 64 + cp * 8 + (key & 7)] = f2bf(p);
      }
    }
    bf16x8 pf[2];
#pragma unroll
    for (int ksl = 0; ksl < 2; ++ksl) {
      const int c = (ksl * 4 + g) ^ (l15 & 7);
      pf[ksl] = *(const bf16x8*)(&Ps[wave][l15 * 64 + c * 8]);
    }
    __builtin_amdgcn_s_setprio(1);
#pragma unroll
    for (int nd = 0; nd < 8; ++nd) {
      const int vrow = nd * 16 + l15;
#pragma unroll
      for (int ksl = 0; ksl < 2; ++ksl) {
        const int c = (ksl * 4 + g) ^ (vrow & 7);
        const bf16x8 vf = *(const bf16x8*)(&Vs[cur][vrow * 64 + c * 8]);
        o[nd] = MFMA16(pf[ksl], vf, o[nd]);
      }
    }
    __builtin_amdgcn_s_setprio(0);

    __syncthreads();
    cur ^= 1;
  }

  float inv[4];
#pragma unroll
  for (int r = 0; r < 4; ++r) {
    float sum = lrun[r];
    sum += __shfl_xor(sum, 1);
    sum += __shfl_xor(sum, 2);
    sum += __shfl_xor(sum, 4);
    sum += __shfl_xor(sum, 8);
    inv[r] = 1.0f / sum;
  }
#pragma unroll
  for (int nd = 0; nd < 8; ++nd) {
#pragma unroll
    for (int r = 0; r < 4; ++r) {
      const int qr = qt * 64 + wave * 16 + g * 4 + r;
      outb[(size_t)qr * 3584 + head * 128 + nd * 16 + l15] = f2bf(o[nd][r] * inv[r]);
    }
  }
#undef STAGE
}

extern "C" void kernel_launch(void* const* d_in, const int* in_sizes, int n_in,
                              void* d_out, int out_size, void* d_ws, size_t ws_size,
                              hipStream_t stream) {
  const float* h  = (const float*)d_in[0];
  const int* pos  = (const int*)d_in[1];
  const float* Wq = (const float*)d_in[2];
  const float* bq = (const float*)d_in[3];
  const float* Wk = (const float*)d_in[4];
  const float* bk = (const float*)d_in[5];
  const float* Wv = (const float*)d_in[6];
  const float* bv = (const float*)d_in[7];
  const float* Wo = (const float*)d_in[8];
  float* out = (float*)d_out;

  char* w = (char*)d_ws;
  short* hbf  = (short*)w; w += (size_t)2048 * 3584 * 2;   // 14.7 MB
  short* Wall = (short*)w; w += (size_t)4608 * 3584 * 2;   // 33.0 MB
  short* Wob  = (short*)w; w += (size_t)3584 * 3584 * 2;   // 25.7 MB
  float* ball = (float*)w; w += 4608 * 4;
  short* qkvp = (short*)w; w += (size_t)2048 * 4608 * 2;   // 18.9 MB
  float* ctab = (float*)w; w += 2048 * 64 * 4;
  float* stab = (float*)w; w += 2048 * 64 * 4;
  short* vtb  = (short*)w; w += (size_t)4 * 128 * 2048 * 2;
  short* Pp   = (short*)w; w += (size_t)224 * 65536 * 2;   // 28.7 MB partials
  short* attnb = hbf;  // hbf dead after QKV GEMM

  // cvt (h,Wq,Wk,Wv) + rope table + bias concat, one launch
  setup_all<<<2304, 256, 0, stream>>>(h, Wq, Wk, Wv, hbf, Wall, pos, ctab, stab,
                                      bq, bk, bv, ball);

  // QKV GEMM on blocks 0..143 + Wo cvt on blocks 144..255 (hetero).
  gemm11<256, 18, 2, 9, true, true, true><<<256, 512, 0, stream>>>(
      hbf, Wall, ball, qkvp, 4608, 3584, Wo, Wob);

  // RoPE (q,k) + V transpose, one launch
  rope_vt<<<2560, 256, 0, stream>>>(qkvp, ctab, stab, vtb);

  attn_kernel<<<896, 256, 0, stream>>>(qkvp, vtb, attnb);

  // O-proj: split-K-2, 224 blocks x 28 K-tiles -> partials -> reduce.
  gemm_osp<<<224, 512, 0, stream>>>(attnb, Wob, Pp, 3584);
  o_reduce<<<3584, 256, 0, stream>>>(Pp, out);
}

// Round 17
// 223.851 us; speedup vs baseline: 1.0727x; 1.0727x over previous
//
#include <hip/hip_runtime.h>

typedef __attribute__((ext_vector_type(4))) float f32x4;
typedef __attribute__((ext_vector_type(8))) short bf16x8;

#define MFMA16(a, b, c) __builtin_amdgcn_mfma_f32_16x16x32_bf16((a), (b), (c), 0, 0, 0)
#define LOG2E 1.44269504088896340736f

static __device__ __forceinline__ float bf2f(short u) {
  unsigned x = ((unsigned)(unsigned short)u) << 16;
  return __builtin_bit_cast(float, x);
}
static __device__ __forceinline__ short f2bf(float f) {
  unsigned u = __builtin_bit_cast(unsigned, f);
  u += 0x7fffu + ((u >> 16) & 1u);
  return (short)(u >> 16);
}
// global -> LDS direct DMA, 16B per lane (guide §5); source pre-swizzled.
static __device__ __forceinline__ void gll16(const void* g, void* l) {
  __builtin_amdgcn_global_load_lds(
      (const __attribute__((address_space(1))) unsigned*)(unsigned long long)g,
      (__attribute__((address_space(3))) unsigned*)(unsigned)(unsigned long long)l,
      16, 0, 0);
}

// --- merged setup: f32->bf16 cvt (h,Wq,Wk,Wv) + rope table + bias concat ---
__global__ void __launch_bounds__(256) setup_all(const float* __restrict__ h,
                                                 const float* __restrict__ wq,
                                                 const float* __restrict__ wk,
                                                 const float* __restrict__ wv,
                                                 short* __restrict__ hbf,
                                                 short* __restrict__ wall,
                                                 const int* __restrict__ pos,
                                                 float* __restrict__ ctab,
                                                 float* __restrict__ stab,
                                                 const float* __restrict__ bq,
                                                 const float* __restrict__ bk,
                                                 const float* __restrict__ bv,
                                                 float* __restrict__ ball) {
  const int bid = (int)blockIdx.x;
  const int tid = (int)threadIdx.x;
  if (bid >= 2048) {
    const int rb = bid - 2048;  // 0..255
    if (rb < 18) {
      const int i = rb * 256 + tid;
      if (i < 3584) ball[i] = bq[i];
      else if (i < 4096) ball[i] = bk[i - 3584];
      else if (i < 4608) ball[i] = bv[i - 4096];
    }
#pragma unroll
    for (int e = 0; e < 2; ++e) {
      const int ii = (rb * 256 + tid) * 2 + e;  // 0..131071
      const int s = ii >> 6, i = ii & 63;
      const float p = (float)pos[s];
      const float ang = p * exp2f(-(float)i * 0.3114307588956902f);
      ctab[s * 64 + i] = cosf(ang);
      stab[s * 64 + i] = sinf(ang);
    }
    return;
  }
  const long long C0 = 917504, C1 = 1605632, C2 = 229376;  // 8-elem chunks
  long long ch = (long long)bid * 256 + tid;
  const long long stride = (long long)2048 * 256;
  const long long total = C0 + C1 + 2 * C2;
  for (; ch < total; ch += stride) {
    const float* s;
    short* d;
    long long off;
    if (ch < C0) { s = h; d = hbf; off = ch; }
    else if (ch < C0 + C1) { s = wq; d = wall; off = ch - C0; }
    else if (ch < C0 + C1 + C2) { s = wk; d = wall + (size_t)3584 * 3584; off = ch - C0 - C1; }
    else { s = wv; d = wall + (size_t)4096 * 3584; off = ch - C0 - C1 - C2; }
    const long long i = off * 8;
    f32x4 a = *(const f32x4*)(s + i);
    f32x4 b = *(const f32x4*)(s + i + 4);
    bf16x8 o;
    o[0] = f2bf(a[0]); o[1] = f2bf(a[1]); o[2] = f2bf(a[2]); o[3] = f2bf(a[3]);
    o[4] = f2bf(b[0]); o[5] = f2bf(b[1]); o[6] = f2bf(b[2]); o[7] = f2bf(b[3]);
    *(bf16x8*)(d + i) = o;
  }
}

// --- fused RoPE (in-place on qkv q/k regions) + V transpose -> vtb ---------
__global__ void __launch_bounds__(256) rope_vt(short* __restrict__ qkv,
                                               const float* __restrict__ ctab,
                                               const float* __restrict__ stab,
                                               short* __restrict__ vtb) {
  const int bid = (int)blockIdx.x;
  const int tid = (int)threadIdx.x;
  if (bid >= 2048) {
    __shared__ short t[64 * 48];
    const int vb = bid - 2048;  // 0..511
    const int dt = vb & 3, st = (vb >> 2) & 31, kv = vb >> 7;
    {
      const int r = tid >> 2, c8 = tid & 3;
      const bf16x8 v = *(const bf16x8*)(qkv + (size_t)(st * 64 + r) * 4608 + 4096 +
                                        kv * 128 + dt * 32 + c8 * 8);
      *(bf16x8*)(t + r * 48 + c8 * 8) = v;
    }
    __syncthreads();
    {
      const int d = tid >> 3, c = tid & 7;
      bf16x8 v;
#pragma unroll
      for (int i = 0; i < 8; ++i) v[i] = t[(c * 8 + i) * 48 + d];
      *(bf16x8*)(vtb + ((size_t)kv * 128 + dt * 32 + d) * 2048 + st * 64 + c * 8) = v;
    }
    return;
  }
  const int idx = bid * 256 + tid;  // 2048*32*8
  const int c = idx & 7;
  const int h = (idx >> 3) & 31;
  const int s = idx >> 8;
  const float qs = (h < 28) ? (0.08838834764831845f * LOG2E) : 1.0f;
  short* base = qkv + (size_t)s * 4608 + h * 128 + c * 8;
  bf16x8 lo = *(bf16x8*)base;
  bf16x8 hi = *(bf16x8*)(base + 64);
  const float* cp = ctab + s * 64 + c * 8;
  const float* sp = stab + s * 64 + c * 8;
  bf16x8 lo2, hi2;
#pragma unroll
  for (int j = 0; j < 8; ++j) {
    const float x = bf2f(lo[j]), y = bf2f(hi[j]);
    const float cv = cp[j], sv = sp[j];
    lo2[j] = f2bf((x * cv - y * sv) * qs);
    hi2[j] = f2bf((y * cv + x * sv) * qs);
  }
  *(bf16x8*)base = lo2;
  *(bf16x8*)(base + 64) = hi2;
}

// --- 8-phase bf16 GEMM, read-ahead tails (r7/r14-proven, ~88 us) ------------
// C[M=2048,N] = A[M,K]*B[N,K]^T (+bias). BMx256 tile, 8 waves (2M x 4N),
// BK=64, 2 K-tiles/iter double-buffered. Phase = {bar; lgkmcnt(0);
// sched_barrier; 16 MFMA setprio'd; tail: STG -> [VMW] -> READ next frags}.
// Lockstep per-tile blocks -> same-instant L2 sharing (FETCH ~104 MB; all
// stream-K/split-K variants regressed). 2D XCD chunking: xcd=bid&7 owns an
// MCHxNCH tile rect. HETERO: blocks with idx >= MCH*NCH convert Wo instead.
template <int BM, int NT, int MCH, int NCH, bool BIAS, bool OUTBF, bool HETERO>
__global__ void __launch_bounds__(512, 2)
gemm10(const short* __restrict__ A, const short* __restrict__ B,
       const float* __restrict__ bias, void* __restrict__ outp, int N, int K,
       const float* __restrict__ xsrc, short* __restrict__ xdst) {
  constexpr int MQ2 = BM / 64;     // m-frags per rh-half (256->4, 128->2)
  constexpr int ACH = BM / 128;    // gll16 calls per A half-tile
  __shared__ short As[2][BM * 64];
  __shared__ short Bs[2][256 * 64];
  const int bid = (int)blockIdx.x;
  const int tid = (int)threadIdx.x;
  if (HETERO && (bid >> 3) >= MCH * NCH) {
    // cvt role: blocks 144..255 convert Wo (f32 -> bf16), grid-stride.
    const int cb = bid - 8 * MCH * NCH;  // 0..111
    long long i = ((long long)cb * 512 + tid) * 8;
    const long long stride = (long long)112 * 512 * 8;
    const long long n = (long long)3584 * 3584;
    for (; i < n; i += stride) {
      f32x4 a = *(const f32x4*)(xsrc + i);
      f32x4 b = *(const f32x4*)(xsrc + i + 4);
      bf16x8 o;
      o[0] = f2bf(a[0]); o[1] = f2bf(a[1]); o[2] = f2bf(a[2]); o[3] = f2bf(a[3]);
      o[4] = f2bf(b[0]); o[5] = f2bf(b[1]); o[6] = f2bf(b[2]); o[7] = f2bf(b[3]);
      *(bf16x8*)(xdst + i) = o;
    }
    return;
  }
  const int xcd = bid & 7, idx = bid >> 3;
  const int rowg = xcd / (NT / NCH), colg = xcd % (NT / NCH);
  const int tm = (rowg * MCH + idx % MCH) * BM;
  const int tn = (colg * NCH + idx / MCH) * 256;
  const int wave = tid >> 6, lane = tid & 63;
  const int l15 = lane & 15, g = lane >> 4;
  const int wm = wave >> 2, wn = wave & 3;

  f32x4 acc[2][MQ2][2][2] = {};  // [rh][mq][ch][nq]
  bf16x8 af[MQ2][2], b0[2][2], b1[2][2];

#define STG_A(b, kt, h)                                                         \
  { _Pragma("unroll") for (int j = 0; j < ACH; ++j) {                           \
      const int lr = (h) * (BM / 2) + j * 64 + (tid >> 3);                      \
      const int wmm = (lr / (BM / 4)) & 1;                                      \
      const int rr = lr & (BM / 4 - 1);                                         \
      const int grow = wmm * (BM / 2) + (h) * (BM / 4) + rr;                    \
      const int sc = (tid & 7) ^ (rr & 7);                                      \
      gll16(A + (size_t)(tm + grow) * K + (size_t)(kt) * 64 + sc * 8,           \
            &As[b][((h) * (BM / 2) + j * 64 + wave * 8) * 64]);                 \
    } }
#define STG_B(b, kt, h)                                                         \
  { _Pragma("unroll") for (int j = 0; j < 2; ++j) {                             \
      const int lr = (h) * 128 + j * 64 + (tid >> 3);                           \
      const int wnn = (lr >> 5) & 3;                                            \
      const int rr = lr & 31;                                                   \
      const int gcol = wnn * 64 + (h) * 32 + rr;                                \
      const int sc = (tid & 7) ^ (rr & 7);                                      \
      gll16(B + (size_t)(tn + gcol) * K + (size_t)(kt) * 64 + sc * 8,           \
            &Bs[b][((h) * 128 + j * 64 + wave * 8) * 64]);                      \
    } }
#define LDA(buf, rh)                                                            \
  { _Pragma("unroll") for (int mq = 0; mq < MQ2; ++mq)                          \
      _Pragma("unroll") for (int ks = 0; ks < 2; ++ks) {                        \
        const int lr = (rh) * (BM / 2) + wm * (BM / 4) + mq * 16 + l15;         \
        af[mq][ks] =                                                            \
            *(const bf16x8*)(&As[buf][lr * 64 + (((ks * 4 + g) ^ (lr & 7)) * 8)]); \
      } }
#define LDB(buf, ch, ARR)                                                       \
  { _Pragma("unroll") for (int nq = 0; nq < 2; ++nq)                            \
      _Pragma("unroll") for (int ks = 0; ks < 2; ++ks) {                        \
        const int lr = (ch) * 128 + wn * 32 + nq * 16 + l15;                    \
        ARR[nq][ks] =                                                           \
            *(const bf16x8*)(&Bs[buf][lr * 64 + (((ks * 4 + g) ^ (lr & 7)) * 8)]); \
      } }
#define VMW()                                                                   \
  { if constexpr (ACH == 2) { asm volatile("s_waitcnt vmcnt(4)" ::: "memory"); }\
    else { asm volatile("s_waitcnt vmcnt(3)" ::: "memory"); } }
#define PH(RH, CH, BARR, TAILBLK)                                               \
  {                                                                             \
    __builtin_amdgcn_s_barrier();                                               \
    asm volatile("s_waitcnt lgkmcnt(0)" ::: "memory");                          \
    __builtin_amdgcn_sched_barrier(0);                                          \
    __builtin_amdgcn_s_setprio(1);                                              \
    _Pragma("unroll") for (int mq = 0; mq < MQ2; ++mq)                          \
      _Pragma("unroll") for (int nq = 0; nq < 2; ++nq) {                        \
        acc[RH][mq][CH][nq] = MFMA16(af[mq][0], BARR[nq][0], acc[RH][mq][CH][nq]); \
        acc[RH][mq][CH][nq] = MFMA16(af[mq][1], BARR[nq][1], acc[RH][mq][CH][nq]); \
      }                                                                         \
    __builtin_amdgcn_s_setprio(0);                                              \
    TAILBLK;                                                                    \
    __builtin_amdgcn_sched_barrier(0);                                          \
  }

  // prologue: stage t0+t1; wait t0 landed; barrier; read P1's frags.
  STG_A(0, 0, 0); STG_A(0, 0, 1); STG_B(0, 0, 0); STG_B(0, 0, 1);
  STG_A(1, 1, 0); STG_A(1, 1, 1); STG_B(1, 1, 0); STG_B(1, 1, 1);
  if constexpr (ACH == 2) { asm volatile("s_waitcnt vmcnt(8)" ::: "memory"); }
  else                    { asm volatile("s_waitcnt vmcnt(6)" ::: "memory"); }
  __builtin_amdgcn_s_barrier();
  LDA(0, 0); LDB(0, 0, b0);

  const int L = K >> 7;  // 28 iterations, 2 K-tiles each
  for (int i = 0; i < L; ++i) {
    const int t2 = 2 * i + 2, t3 = 2 * i + 3;
    const bool more = (i < L - 1);
    PH(0, 0, b0, { LDB(0, 1, b1); });
    PH(0, 1, b1, { if (more) STG_A(0, t2, 0); LDA(0, 1); });
    PH(1, 1, b1, { if (more) { STG_B(0, t2, 1); VMW(); }
                   else { asm volatile("s_waitcnt vmcnt(0)" ::: "memory"); } });
    PH(1, 0, b0, { if (more) { STG_A(0, t2, 1); STG_B(0, t2, 0); }
                   LDA(1, 0); LDB(1, 0, b0); });
    PH(0, 0, b0, { LDB(1, 1, b1); });
    PH(0, 1, b1, { if (more) STG_A(1, t3, 0); LDA(1, 1); });
    PH(1, 1, b1, { if (more) { STG_B(1, t3, 1); VMW(); } });
    PH(1, 0, b0, { if (more) { STG_A(1, t3, 1); STG_B(1, t3, 0);
                               LDA(0, 0); LDB(0, 0, b0); } });
  }
#undef STG_A
#undef STG_B
#undef LDA
#undef LDB
#undef VMW
#undef PH

  // epilogue: 16x16 C/D layout col=lane&15, row=(lane>>4)*4+reg
#pragma unroll
  for (int rh = 0; rh < 2; ++rh)
#pragma unroll
    for (int mq = 0; mq < MQ2; ++mq)
#pragma unroll
      for (int ch = 0; ch < 2; ++ch)
#pragma unroll
        for (int nq = 0; nq < 2; ++nq) {
          const int col = tn + wn * 64 + ch * 32 + nq * 16 + l15;
          const float bv = BIAS ? bias[col] : 0.0f;
          const int row0 = tm + wm * (BM / 2) + rh * (BM / 4) + mq * 16 + g * 4;
#pragma unroll
          for (int r = 0; r < 4; ++r) {
            const float v = acc[rh][mq][ch][nq][r] + bv;
            if (OUTBF) ((short*)outp)[(size_t)(row0 + r) * N + col] = f2bf(v);
            else       ((float*)outp)[(size_t)(row0 + r) * N + col] = v;
          }
        }
}

// ------- flash attention, 2-phase pipelined, 896 blocks (longest-first) -----
__global__ void __launch_bounds__(256) attn_kernel(const short* __restrict__ qkv,
                                                   const short* __restrict__ vtb,
                                                   short* __restrict__ outb) {
  const int lid = (int)blockIdx.x;   // 0..895, dispatched in order
  const int head = lid % 28;
  const int qt = 31 - lid / 28;      // longest q-tiles first
  const int kvh = head / 7;

  const int tid = threadIdx.x;
  const int lane = tid & 63, wave = tid >> 6;
  const int l15 = lane & 15, g = lane >> 4;

  __shared__ short Ks[2][64 * 128];
  __shared__ short Vs[2][128 * 64];
  __shared__ short Ps[4][16 * 64];

  const short* kbase = qkv + 3584 + kvh * 128;
  const short* vbase = vtb + (size_t)kvh * 128 * 2048;
  const float NINF = -__builtin_inff();

  bf16x8 qf[4];
  {
    const short* qptr = qkv + (size_t)(qt * 64 + wave * 16 + l15) * 4608 + head * 128 + g * 8;
#pragma unroll
    for (int ds = 0; ds < 4; ++ds) qf[ds] = *(const bf16x8*)(qptr + ds * 32);
  }
  f32x4 o[8] = {};
  float mrun[4] = {NINF, NINF, NINF, NINF};
  float lrun[4] = {0.f, 0.f, 0.f, 0.f};

#define STAGE(kv, b)                                                               \
  {                                                                                \
    _Pragma("unroll") for (int it = 0; it < 4; ++it) {                             \
      const int chunk = it * 256 + tid;                                            \
      const int row = chunk >> 4, sc = (chunk & 15) ^ (row & 7);                   \
      gll16(kbase + (size_t)((kv)*64 + row) * 4608 + sc * 8,                       \
            &Ks[b][(it * 256 + wave * 64) * 8]);                                   \
    }                                                                              \
    _Pragma("unroll") for (int it = 0; it < 4; ++it) {                             \
      const int chunk = it * 256 + tid;                                            \
      const int row = chunk >> 3, sc = (chunk & 7) ^ (row & 7);                    \
      gll16(vbase + (size_t)row * 2048 + (kv)*64 + sc * 8,                         \
            &Vs[b][(it * 256 + wave * 64) * 8]);                                   \
    }                                                                              \
  }

  STAGE(0, 0);
  __syncthreads();
  int cur = 0;

#pragma unroll 1
  for (int t = 0; t <= qt; ++t) {
    if (t < qt) STAGE(t + 1, cur ^ 1);
    const bool diag = (t == qt);

    f32x4 sf[4] = {};
    __builtin_amdgcn_s_setprio(1);
#pragma unroll
    for (int n = 0; n < 4; ++n) {
      const int krow = n * 16 + l15;
#pragma unroll
      for (int ds = 0; ds < 4; ++ds) {
        const int c = (ds * 4 + g) ^ (krow & 7);
        const bf16x8 kf = *(const bf16x8*)(&Ks[cur][krow * 128 + c * 8]);
        sf[n] = MFMA16(qf[ds], kf, sf[n]);
      }
    }
    __builtin_amdgcn_s_setprio(0);

    if (diag) {
#pragma unroll
      for (int r = 0; r < 4; ++r) {
        const int qr = qt * 64 + wave * 16 + g * 4 + r;
#pragma unroll
        for (int n = 0; n < 4; ++n)
          if (t * 64 + n * 16 + l15 > qr) sf[n][r] = NINF;
      }
    }
    float pmax[4];
#pragma unroll
    for (int r = 0; r < 4; ++r)
      pmax[r] = fmaxf(fmaxf(sf[0][r], sf[1][r]), fmaxf(sf[2][r], sf[3][r]));
    const bool need = (pmax[0] > mrun[0] + 8.f) || (pmax[1] > mrun[1] + 8.f) ||
                      (pmax[2] > mrun[2] + 8.f) || (pmax[3] > mrun[3] + 8.f);
    if (__any(need)) {
#pragma unroll
      for (int r = 0; r < 4; ++r) {
        float mx = pmax[r];
        mx = fmaxf(mx, __shfl_xor(mx, 1));
        mx = fmaxf(mx, __shfl_xor(mx, 2));
        mx = fmaxf(mx, __shfl_xor(mx, 4));
        mx = fmaxf(mx, __shfl_xor(mx, 8));
        const float mnew = fmaxf(mrun[r], mx);
        const float alpha = exp2f(mrun[r] - mnew);
        mrun[r] = mnew;
        lrun[r] *= alpha;
#pragma unroll
        for (int nd = 0; nd < 8; ++nd) o[nd][r] *= alpha;
      }
    }
#pragma unroll
    for (int n = 0; n < 4; ++n) {
#pragma unroll
      for (int r = 0; r < 4; ++r) {
        const float p = exp2f(sf[n][r] - mrun[r]);
        lrun[r] += p;
        const int prow = g * 4 + r, key = n * 16 + l15;
        const int cp = (key >> 3) ^ (prow & 7);
        Ps[wave][prow * 64 + cp * 8 + (key & 7)] = f2bf(p);
      }
    }
    bf16x8 pf[2];
#pragma unroll
    for (int ksl = 0; ksl < 2; ++ksl) {
      const int c = (ksl * 4 + g) ^ (l15 & 7);
      pf[ksl] = *(const bf16x8*)(&Ps[wave][l15 * 64 + c * 8]);
    }
    __builtin_amdgcn_s_setprio(1);
#pragma unroll
    for (int nd = 0; nd < 8; ++nd) {
      const int vrow = nd * 16 + l15;
#pragma unroll
      for (int ksl = 0; ksl < 2; ++ksl) {
        const int c = (ksl * 4 + g) ^ (vrow & 7);
        const bf16x8 vf = *(const bf16x8*)(&Vs[cur][vrow * 64 + c * 8]);
        o[nd] = MFMA16(pf[ksl], vf, o[nd]);
      }
    }
    __builtin_amdgcn_s_setprio(0);

    __syncthreads();
    cur ^= 1;
  }

  float inv[4];
#pragma unroll
  for (int r = 0; r < 4; ++r) {
    float sum = lrun[r];
    sum += __shfl_xor(sum, 1);
    sum += __shfl_xor(sum, 2);
    sum += __shfl_xor(sum, 4);
    sum += __shfl_xor(sum, 8);
    inv[r] = 1.0f / sum;
  }
#pragma unroll
  for (int nd = 0; nd < 8; ++nd) {
#pragma unroll
    for (int r = 0; r < 4; ++r) {
      const int qr = qt * 64 + wave * 16 + g * 4 + r;
      outb[(size_t)qr * 3584 + head * 128 + nd * 16 + l15] = f2bf(o[nd][r] * inv[r]);
    }
  }
#undef STAGE
}

extern "C" void kernel_launch(void* const* d_in, const int* in_sizes, int n_in,
                              void* d_out, int out_size, void* d_ws, size_t ws_size,
                              hipStream_t stream) {
  const float* h  = (const float*)d_in[0];
  const int* pos  = (const int*)d_in[1];
  const float* Wq = (const float*)d_in[2];
  const float* bq = (const float*)d_in[3];
  const float* Wk = (const float*)d_in[4];
  const float* bk = (const float*)d_in[5];
  const float* Wv = (const float*)d_in[6];
  const float* bv = (const float*)d_in[7];
  const float* Wo = (const float*)d_in[8];
  float* out = (float*)d_out;

  char* w = (char*)d_ws;
  short* hbf  = (short*)w; w += (size_t)2048 * 3584 * 2;   // 14.7 MB
  short* Wall = (short*)w; w += (size_t)4608 * 3584 * 2;   // 33.0 MB
  short* Wob  = (short*)w; w += (size_t)3584 * 3584 * 2;   // 25.7 MB
  float* ball = (float*)w; w += 4608 * 4;
  short* qkvp = (short*)w; w += (size_t)2048 * 4608 * 2;   // 18.9 MB
  float* ctab = (float*)w; w += 2048 * 64 * 4;
  float* stab = (float*)w; w += 2048 * 64 * 4;
  short* vtb  = (short*)w; w += (size_t)4 * 128 * 2048 * 2;
  short* attnb = hbf;  // hbf dead after QKV GEMM

  // cvt (h,Wq,Wk,Wv) + rope table + bias concat, one launch
  setup_all<<<2304, 256, 0, stream>>>(h, Wq, Wk, Wv, hbf, Wall, pos, ctab, stab,
                                      bq, bk, bv, ball);

  // QKV GEMM on blocks 0..143 (2x9 XCD rects, lockstep L2 sharing) +
  // Wo f32->bf16 conversion on blocks 144..255 (otherwise-idle CUs).
  gemm10<256, 18, 2, 9, true, true, true><<<256, 512, 0, stream>>>(
      hbf, Wall, ball, qkvp, 4608, 3584, Wo, Wob);

  // RoPE (q,k) + V transpose, one launch
  rope_vt<<<2560, 256, 0, stream>>>(qkvp, ctab, stab, vtb);

  attn_kernel<<<896, 256, 0, stream>>>(qkvp, vtb, attnb);

  gemm10<128, 14, 4, 7, false, false, false><<<224, 512, 0, stream>>>(
      attnb, Wob, nullptr, out, 3584, 3584, nullptr, nullptr);
}